// Round 12
// baseline (364.312 us; speedup 1.0000x reference)
//
#include <hip/hip_runtime.h>
#include <hip/hip_bf16.h>

// WorkflowGNN: GCN(32->64)+ReLU, GAT(64->64,h=1)+ReLU, GCN(64->64)+ReLU,
// heads: opt [N,10], bottleneck [N,1], mean-embed [64]. f32 in/out.
// R27: k_heads regressed to 54us in R26 (BW 2.7%, occ 28%): the fused-mean
// xr[fk] per-lane load knocked the row reads off the SCALAR path (v is
// SGPR-uniform -> s_load_dwordx4), and acc is a 64-deep fmaf chain at 4
// waves/SIMD. Fix: (1) femb via compile-time-predicated pick from the
// uniform loads (myw = (k8==fk)?wd:myw) -- zero extra loads; (2) 4-way
// accumulator split (ac[k8&3], static idx) in k_heads/k_gemm_b/k_gemm_alpha;
// (3) grid 1024->2048 on those (8 waves/SIMD).
// R26 (kept): gat_agg single-pass adjacency (u8/p8 in regs); mean fused in
// k_heads; R25 batch arrays dropped.
// R24 (kept): in-bucket degree sort in k_fill (perm) -> cmax ~ deg.
// R22 (kept): 8-node/wave aggs, no butterfly, adj pad slots = n (zero row),
// fused castscale in k_fill.
// R20 (kept): k_agg32g epilogue via constant-index v_readlane.
// R19 (kept): atomic-free adjacency build (exact buckets + LDS fill).

#define CAP 64
#define NP2 128          // nodes per bucket (LDS tile rows), = 1<<7
#define NB2MAX 800       // LDS cursor array bound (n <= 102400)

__device__ __forceinline__ int uwave(){                 // wave id, known-uniform
  return __builtin_amdgcn_readfirstlane(threadIdx.x >> 6);
}
__device__ __forceinline__ unsigned short f2bf(float f){ // RNE, finite inputs
  unsigned u = __float_as_uint(f);
  return (unsigned short)((u + 0x7fffu + ((u >> 16) & 1u)) >> 16);
}
__device__ __forceinline__ float bfl(unsigned u){ return __uint_as_float(u << 16); }
__device__ __forceinline__ float bfh(unsigned u){ return __uint_as_float(u & 0xffff0000u); }
__device__ __forceinline__ float rdlane(float v, int l){ // constant-lane broadcast
  return __uint_as_float(__builtin_amdgcn_readlane(__float_as_uint(v), l));
}

// setup: zero bcnt/pad-rows/emb_acc/als[n], pack Wcat/bcat
__global__ void k_setup(const float* __restrict__ Wopt, const float* __restrict__ bopt,
                        const float* __restrict__ Wb1, const float* __restrict__ bb1,
                        float* __restrict__ Wcat, float* __restrict__ bcat,
                        int* __restrict__ bcnt, unsigned short* __restrict__ tb,
                        unsigned short* __restrict__ xh, float* __restrict__ emb_acc,
                        float* __restrict__ als, int n, int nb2){
  int i = blockIdx.x*blockDim.x + threadIdx.x;
  if (i < nb2) bcnt[i] = 0;
  if (blockIdx.x == 0){
    int tid = threadIdx.x;
    for (int j = tid; j < 4096; j += 256){    // pack head weights
      int f = j >> 6, c = j & 63;
      float w = 0.f;
      if (c < 10)       w = Wopt[f*10 + c];
      else if (c >= 32) w = Wb1[f*32 + (c-32)];
      Wcat[j] = w;
    }
    if (tid < 64){
      float b = 0.f;
      if (tid < 10)       b = bopt[tid];
      else if (tid >= 32) b = bb1[tid-32];
      bcat[tid] = b;
      tb[(size_t)n*64 + tid] = 0;             // zero pad row (64-feat)
      emb_acc[tid] = 0.f;
      if (tid == 0) als[n] = 0.f;             // pad score
    }
    if (tid >= 64 && tid < 96) xh[(size_t)n*32 + (tid-64)] = 0;  // zero pad row (32-feat)
  }
}

// pass A: bin edges into exact dst-range buckets (bk = dst>>7). One coalesced
// read of src/dst, LDS-aggregated cursors -> ~nb2 global atomics per block.
__global__ __launch_bounds__(256) void k_part(const int* __restrict__ src,
                        const int* __restrict__ dst,
                        uint2* __restrict__ pairs, int* __restrict__ bcnt,
                        int e, int nb2, int pbcap){
  __shared__ int lcnt[NB2MAX];
  __shared__ int lbase[NB2MAX];
  int tid = threadIdx.x;
  for (int j = tid; j < nb2; j += 256) lcnt[j] = 0;
  __syncthreads();
  int i0 = blockIdx.x*2048 + tid*8;
  int d[8], s[8], bk[8], lp[8];
  int nv = e - i0;
  if (nv > 8) nv = 8;
  if (nv < 0) nv = 0;
  if (nv == 8){
    int4 d0 = *(const int4*)(dst + i0), d1 = *(const int4*)(dst + i0 + 4);
    int4 s0 = *(const int4*)(src + i0), s1 = *(const int4*)(src + i0 + 4);
    d[0]=d0.x; d[1]=d0.y; d[2]=d0.z; d[3]=d0.w;
    d[4]=d1.x; d[5]=d1.y; d[6]=d1.z; d[7]=d1.w;
    s[0]=s0.x; s[1]=s0.y; s[2]=s0.z; s[3]=s0.w;
    s[4]=s1.x; s[5]=s1.y; s[6]=s1.z; s[7]=s1.w;
  } else {
    #pragma unroll
    for (int j = 0; j < 8; j++){ d[j] = 0; s[j] = 0; }
    for (int j = 0; j < nv; j++){ d[j] = dst[i0+j]; s[j] = src[i0+j]; }
  }
  #pragma unroll
  for (int j = 0; j < 8; j++){
    if (j < nv){
      bk[j] = d[j] >> 7;                      // exact: bucket owns [bk*128, bk*128+128)
      lp[j] = atomicAdd(&lcnt[bk[j]], 1);
    }
  }
  __syncthreads();
  for (int j = tid; j < nb2; j += 256){
    int c = lcnt[j];
    if (c) lbase[j] = atomicAdd(&bcnt[j], c);
  }
  __syncthreads();
  #pragma unroll
  for (int j = 0; j < 8; j++){
    if (j < nv){
      int p = lbase[bk[j]] + lp[j];
      if (p < pbcap)
        pairs[(size_t)bk[j]*pbcap + p] = make_uint2((unsigned)d[j], (unsigned)s[j]);
    }
  }
}

// pass B: one block per bucket. adj rows built in LDS (LDS atomics only),
// slots pre-initialized to n (zero-row index). Emits IN-BUCKET degree-sorted
// perm (65-bin LDS counting sort) + fused cast-scale of its 128 x-rows.
__global__ __launch_bounds__(256) void k_fill(const uint2* __restrict__ pairs,
                        const int* __restrict__ bcnt, int* __restrict__ cnt,
                        int* __restrict__ adj, int* __restrict__ perm,
                        const float* __restrict__ x, unsigned short* __restrict__ xh,
                        int pbcap, int n){
  __shared__ int lc[NP2];
  __shared__ int ladj[NP2*CAP];               // 32KB
  __shared__ int lb[65];
  int b = blockIdx.x;
  int lo = b << 7;
  int nn = min(NP2, n - lo);
  int tid = threadIdx.x;
  for (int j = tid; j < NP2; j += 256) lc[j] = 0;
  if (tid < 65) lb[tid] = 0;
  int4 nfill = make_int4(n, n, n, n);
  for (int j = tid; j < NP2*CAP/4; j += 256) ((int4*)ladj)[j] = nfill;
  __syncthreads();
  int m = bcnt[b];
  if (m > pbcap) m = pbcap;
  const uint2* pb = pairs + (size_t)b*pbcap;
  for (int j = tid; j < m; j += 256){
    uint2 p = pb[j];
    int r = (int)p.x - lo;
    int pos = atomicAdd(&lc[r], 1);
    if (pos < CAP) ladj[(r << 6) + pos] = (int)p.y;
  }
  __syncthreads();
  int d = 0;
  if (tid < nn){
    int c = lc[tid];
    cnt[lo + tid] = c;
    d = min(c, CAP);
    atomicAdd(&lb[d], 1);                     // degree histogram
  }
  __syncthreads();
  if (tid == 0){                              // exclusive scan, 65 bins
    int s = 0;
    #pragma unroll 1
    for (int k = 0; k < 65; k++){ int c = lb[k]; lb[k] = s; s += c; }
  }
  __syncthreads();
  if (tid < nn){                              // scatter: lb doubles as cursor
    int p = atomicAdd(&lb[d], 1);
    perm[lo + p] = lo + tid;                  // in-bucket degree-sorted perm
  }
  int tot = nn << 4;                          // nn*64 ints / 4 per uint4
  uint4* ga = (uint4*)(adj + (size_t)lo*CAP);
  const uint4* la = (const uint4*)ladj;
  for (int j = tid; j < tot; j += 256) ga[j] = la[j];
  // fused cast-scale: nn rows x 32 feats, dv = rsqrt(lc[r]+1)
  int tf = nn << 3;                           // float4 count
  const float4* xr4 = (const float4*)(x + (size_t)lo*32);
  uint2* xo = (uint2*)(xh + (size_t)lo*32);
  for (int j = tid; j < tf; j += 256){
    int r = j >> 3;
    float dv = rsqrtf((float)(lc[r] + 1));
    float4 v = xr4[j];
    uint2 o;
    o.x = (unsigned)f2bf(v.x*dv) | ((unsigned)f2bf(v.y*dv) << 16);
    o.y = (unsigned)f2bf(v.z*dv) | ((unsigned)f2bf(v.w*dv) << 16);
    xo[j] = o;
  }
}

// layer-1 FUSED aggregate+gemm, DUAL-NODE (perm'd: pair degree-adjacent).
__global__ __launch_bounds__(256) void k_agg32g(const unsigned short* __restrict__ xh,
                          const int* __restrict__ adj, const int* __restrict__ cnt,
                          const int* __restrict__ perm,
                          const float* __restrict__ W1, const float* __restrict__ b1,
                          unsigned short* __restrict__ h, int n){
  int lane = threadIdx.x & 63;
  float wreg[32];
  #pragma unroll
  for (int k = 0; k < 32; k++) wreg[k] = W1[k*64 + lane];  // coalesced, once
  float br = b1[lane];
  int i0 = blockIdx.x*8 + uwave()*2;
  if (i0 >= n) return;                        // uniform
  int i1 = i0 + 1;
  bool has1 = i1 < n;
  int v0 = perm[i0];
  int v1 = perm[has1 ? i1 : i0];
  int cn0 = cnt[v0], cn1 = cnt[v1];
  int c0 = min(cn0, CAP), c1 = min(cn1, CAP);
  int ureg0 = n, ureg1 = n;                   // pad -> zero row
  if (lane < c0) ureg0 = (adj + (size_t)v0*CAP)[lane];
  if (lane < c1) ureg1 = (adj + (size_t)v1*CAP)[lane];
  int g = lane >> 3, q = lane & 7;
  float4 a0 = {0.f,0.f,0.f,0.f}, a1 = {0.f,0.f,0.f,0.f};
  int itm = (max(c0, c1) + 7) >> 3;           // degree-adjacent pair: ~c0/8
  #pragma unroll 2
  for (int jj = 0; jj < itm; jj++){
    int u0 = __shfl(ureg0, jj*8 + g);         // pad iters -> zero row (L1-hot)
    int u1 = __shfl(ureg1, jj*8 + g);
    uint2 r0 = ((const uint2*)(xh + (size_t)u0*32))[q];   // both loads in flight
    uint2 r1 = ((const uint2*)(xh + (size_t)u1*32))[q];
    a0.x += bfl(r0.x); a0.y += bfh(r0.x); a0.z += bfl(r0.y); a0.w += bfh(r0.y);
    a1.x += bfl(r1.x); a1.y += bfh(r1.x); a1.z += bfl(r1.y); a1.w += bfh(r1.y);
  }
  #pragma unroll
  for (int off = 8; off <= 32; off <<= 1){
    a0.x += __shfl_xor(a0.x, off); a0.y += __shfl_xor(a0.y, off);
    a0.z += __shfl_xor(a0.z, off); a0.w += __shfl_xor(a0.w, off);
    a1.x += __shfl_xor(a1.x, off); a1.y += __shfl_xor(a1.y, off);
    a1.z += __shfl_xor(a1.z, off); a1.w += __shfl_xor(a1.w, off);
  }
  uint2 s0 = ((const uint2*)(xh + (size_t)v0*32))[q];     // self rows (pre-scaled)
  uint2 s1 = ((const uint2*)(xh + (size_t)v1*32))[q];
  a0.x += bfl(s0.x); a0.y += bfh(s0.x); a0.z += bfl(s0.y); a0.w += bfh(s0.y);
  a1.x += bfl(s1.x); a1.y += bfh(s1.x); a1.z += bfl(s1.y); a1.w += bfh(s1.y);
  float dv0 = rsqrtf((float)(cn0 + 1)), dv1 = rsqrtf((float)(cn1 + 1));
  a0.x *= dv0; a0.y *= dv0; a0.z *= dv0; a0.w *= dv0;
  a1.x *= dv1; a1.y *= dv1; a1.z *= dv1; a1.w *= dv1;
  float h0 = br, h1v = br;                    // epilogue gemms via v_readlane (VALU)
  #pragma unroll
  for (int q2 = 0; q2 < 8; q2++){
    float w0x = rdlane(a0.x, q2), w1x = rdlane(a1.x, q2);
    float w0y = rdlane(a0.y, q2), w1y = rdlane(a1.y, q2);
    float w0z = rdlane(a0.z, q2), w1z = rdlane(a1.z, q2);
    float w0w = rdlane(a0.w, q2), w1w = rdlane(a1.w, q2);
    h0 = fmaf(w0x, wreg[q2*4+0], h0); h1v = fmaf(w1x, wreg[q2*4+0], h1v);
    h0 = fmaf(w0y, wreg[q2*4+1], h0); h1v = fmaf(w1y, wreg[q2*4+1], h1v);
    h0 = fmaf(w0z, wreg[q2*4+2], h0); h1v = fmaf(w1z, wreg[q2*4+2], h1v);
    h0 = fmaf(w0w, wreg[q2*4+3], h0); h1v = fmaf(w1w, wreg[q2*4+3], h1v);
  }
  h[(size_t)v0*64 + lane] = f2bf(fmaxf(h0, 0.f));   // 128B store (bucket-local)
  if (has1) h[(size_t)v1*64 + lane] = f2bf(fmaxf(h1v, 0.f));
}

// K=64 GEMM (bf16 in) -> bf16 out, optional pre-scale. 4-way acc split (ILP).
template<bool SCALE>
__global__ __launch_bounds__(256, 4) void k_gemm_b(const unsigned short* __restrict__ x,
                       const float* __restrict__ W, const int* __restrict__ cnt,
                       unsigned short* __restrict__ t, int n){
  int lane = threadIdx.x & 63;
  int gw = blockIdx.x*4 + uwave();
  int nw = gridDim.x*4;
  float wreg[64];
  #pragma unroll
  for (int k = 0; k < 64; k++) wreg[k] = W[k*64 + lane];
  for (int v = gw; v < n; v += nw){
    const uint4* xr = (const uint4*)(x + (size_t)v*64);   // uniform row, 8x16B
    float ac[4] = {0.f, 0.f, 0.f, 0.f};
    #pragma unroll
    for (int k8 = 0; k8 < 8; k8++){
      uint4 c = xr[k8];
      float s = 0.f;
      s = fmaf(bfl(c.x), wreg[k8*8+0], s);
      s = fmaf(bfh(c.x), wreg[k8*8+1], s);
      s = fmaf(bfl(c.y), wreg[k8*8+2], s);
      s = fmaf(bfh(c.y), wreg[k8*8+3], s);
      s = fmaf(bfl(c.z), wreg[k8*8+4], s);
      s = fmaf(bfh(c.z), wreg[k8*8+5], s);
      s = fmaf(bfl(c.w), wreg[k8*8+6], s);
      s = fmaf(bfh(c.w), wreg[k8*8+7], s);
      ac[k8 & 3] += s;                        // static idx (unrolled)
    }
    float acc = (ac[0] + ac[2]) + (ac[1] + ac[3]);
    if (SCALE) acc *= rsqrtf((float)(cnt[v] + 1));
    t[(size_t)v*64 + lane] = f2bf(acc);                    // 128B coalesced
  }
}

// K=64 GEMM + fused alpha dots. 4-way acc split (ILP).
__global__ __launch_bounds__(256, 4) void k_gemm_alpha(const unsigned short* __restrict__ x,
                       const float* __restrict__ W,
                       const float* __restrict__ asrc, const float* __restrict__ adst,
                       unsigned short* __restrict__ t, float* __restrict__ als,
                       float* __restrict__ ald, int n){
  int lane = threadIdx.x & 63;
  int gw = blockIdx.x*4 + uwave();
  int nw = gridDim.x*4;
  float wreg[64];
  #pragma unroll
  for (int k = 0; k < 64; k++) wreg[k] = W[k*64 + lane];
  float asr = asrc[lane], adr = adst[lane];
  for (int v = gw; v < n; v += nw){
    const uint4* xr = (const uint4*)(x + (size_t)v*64);
    float ac[4] = {0.f, 0.f, 0.f, 0.f};
    #pragma unroll
    for (int k8 = 0; k8 < 8; k8++){
      uint4 c = xr[k8];
      float s = 0.f;
      s = fmaf(bfl(c.x), wreg[k8*8+0], s);
      s = fmaf(bfh(c.x), wreg[k8*8+1], s);
      s = fmaf(bfl(c.y), wreg[k8*8+2], s);
      s = fmaf(bfh(c.y), wreg[k8*8+3], s);
      s = fmaf(bfl(c.z), wreg[k8*8+4], s);
      s = fmaf(bfh(c.z), wreg[k8*8+5], s);
      s = fmaf(bfl(c.w), wreg[k8*8+6], s);
      s = fmaf(bfh(c.w), wreg[k8*8+7], s);
      ac[k8 & 3] += s;                        // static idx (unrolled)
    }
    float acc = (ac[0] + ac[2]) + (ac[1] + ac[3]);
    t[(size_t)v*64 + lane] = f2bf(acc);
    float s1 = acc * asr, s2 = acc * adr;
    #pragma unroll
    for (int off = 32; off; off >>= 1){
      s1 += __shfl_xor(s1, off);
      s2 += __shfl_xor(s2, off);
    }
    if (lane == 0){ als[v] = s1; ald[v] = s2; }
  }
}

// GCN agg (layer 3): 8 degree-adjacent nodes/wave via in-bucket perm.
__global__ __launch_bounds__(256) void k_gcn_agg(const unsigned short* __restrict__ t,
                          const int* __restrict__ adj, const int* __restrict__ cnt,
                          const int* __restrict__ perm,
                          const float* __restrict__ b, unsigned short* __restrict__ h, int n){
  int lane = threadIdx.x & 63;
  int g = lane >> 3, q = lane & 7;
  int i0 = blockIdx.x*32 + uwave()*8;
  if (i0 >= n) return;                        // uniform
  int idx = i0 + g;
  bool vok = idx < n;
  int vg = perm[vok ? idx : n - 1];
  int cn = cnt[vg];
  int c = vok ? min(cn, CAP) : 0;
  int cm = c;                                 // wave max degree (~equal, sorted)
  cm = max(cm, __shfl_xor(cm, 8));
  cm = max(cm, __shfl_xor(cm, 16));
  cm = max(cm, __shfl_xor(cm, 32));
  int cmax = __builtin_amdgcn_readfirstlane(cm);
  const int* arow = adj + (size_t)vg*CAP;     // per-lane base
  float a[8] = {0,0,0,0,0,0,0,0};
  int bsel = (lane & 56);
  for (int blk = 0; blk*8 < cmax; blk++){
    int ureg = arow[blk*8 + q];               // 8 slots of own row (pad slots = n)
    #pragma unroll
    for (int j2 = 0; j2 < 8; j2++){
      int u = __shfl(ureg, bsel | j2);        // group-slot broadcast
      uint4 r = ((const uint4*)(t + (size_t)u*64))[q];    // 1KB wave load
      a[0] += bfl(r.x); a[1] += bfh(r.x); a[2] += bfl(r.y); a[3] += bfh(r.y);
      a[4] += bfl(r.z); a[5] += bfh(r.z); a[6] += bfl(r.w); a[7] += bfh(r.w);
    }
  }
  uint4 s = ((const uint4*)(t + (size_t)vg*64))[q];       // self row
  a[0] += bfl(s.x); a[1] += bfh(s.x); a[2] += bfl(s.y); a[3] += bfh(s.y);
  a[4] += bfl(s.z); a[5] += bfh(s.z); a[6] += bfl(s.w); a[7] += bfh(s.w);
  float dv = rsqrtf((float)(cn + 1));
  float4 b0 = ((const float4*)b)[2*q], b1v = ((const float4*)b)[2*q+1];
  float r0 = fmaxf(fmaf(a[0], dv, b0.x), 0.f),  r1 = fmaxf(fmaf(a[1], dv, b0.y), 0.f);
  float r2 = fmaxf(fmaf(a[2], dv, b0.z), 0.f),  r3 = fmaxf(fmaf(a[3], dv, b0.w), 0.f);
  float r4 = fmaxf(fmaf(a[4], dv, b1v.x), 0.f), r5 = fmaxf(fmaf(a[5], dv, b1v.y), 0.f);
  float r6 = fmaxf(fmaf(a[6], dv, b1v.z), 0.f), r7 = fmaxf(fmaf(a[7], dv, b1v.w), 0.f);
  uint4 o;
  o.x = (unsigned)f2bf(r0) | ((unsigned)f2bf(r1) << 16);
  o.y = (unsigned)f2bf(r2) | ((unsigned)f2bf(r3) << 16);
  o.z = (unsigned)f2bf(r4) | ((unsigned)f2bf(r5) << 16);
  o.w = (unsigned)f2bf(r6) | ((unsigned)f2bf(r7) << 16);
  if (vok) ((uint4*)(h + (size_t)vg*64))[q] = o;          // 128B store (bucket-local)
}

// GAT agg: 8 degree-adjacent nodes/wave, SINGLE adjacency pass (u8/p8 regs).
__global__ __launch_bounds__(256) void k_gat_agg(const unsigned short* __restrict__ t,
                          const int* __restrict__ adj, const int* __restrict__ cnt,
                          const int* __restrict__ perm,
                          const float* __restrict__ als, const float* __restrict__ ald,
                          const float* __restrict__ b, unsigned short* __restrict__ h, int n){
  int lane = threadIdx.x & 63;
  int g = lane >> 3, q = lane & 7;
  int i0 = blockIdx.x*32 + uwave()*8;
  if (i0 >= n) return;                        // uniform
  int idx = i0 + g;
  bool vok = idx < n;
  int vg = perm[vok ? idx : n - 1];
  int c = vok ? min(cnt[vg], CAP) : 0;
  int cm = c;
  cm = max(cm, __shfl_xor(cm, 8));
  cm = max(cm, __shfl_xor(cm, 16));
  cm = max(cm, __shfl_xor(cm, 32));
  int cmax = __builtin_amdgcn_readfirstlane(cm);
  const int* arow = adj + (size_t)vg*CAP;
  float adv = ald[vg];
  float es = als[vg] + adv; es = es > 0.f ? es : 0.2f*es;
  int u8[8];
  float p8[8];
  #pragma unroll
  for (int r = 0; r < 8; r++){ u8[r] = n; p8[r] = -1e30f; }
  float em = es;
  #pragma unroll
  for (int r = 0; r < 8; r++){
    if (r*8 >= cmax) break;                   // uniform
    int slot = r*8 + q;
    int u = arow[slot];                       // pad slot -> n (als[n]=0)
    u8[r] = u;
    float ev = als[u] + adv; ev = ev > 0.f ? ev : 0.2f*ev;
    p8[r] = (slot < c) ? ev : -1e30f;
    em = fmaxf(em, p8[r]);
  }
  em = fmaxf(em, __shfl_xor(em, 1));
  em = fmaxf(em, __shfl_xor(em, 2));
  em = fmaxf(em, __shfl_xor(em, 4));
  float sm = 0.f;
  #pragma unroll
  for (int r = 0; r < 8; r++){
    if (r*8 >= cmax) break;                   // uniform
    float pv = __expf(p8[r] - em);            // masked slots -> exp(-1e30)=0
    p8[r] = pv;                               // store final edge weight
    sm += pv;
  }
  sm += __shfl_xor(sm, 1);
  sm += __shfl_xor(sm, 2);
  sm += __shfl_xor(sm, 4);
  float ps = __expf(es - em);
  float inv = 1.f / (sm + ps);
  float a[8] = {0,0,0,0,0,0,0,0};
  int bsel = (lane & 56);
  #pragma unroll
  for (int blk = 0; blk < 8; blk++){          // static idx into u8/p8 (rule #20)
    if (blk*8 >= cmax) break;                 // uniform
    #pragma unroll
    for (int j2 = 0; j2 < 8; j2++){
      int   u = __shfl(u8[blk], bsel | j2);   // group-slot broadcast
      float w = __shfl(p8[blk], bsel | j2);   // precomputed weight (0 for pads)
      uint4 r = ((const uint4*)(t + (size_t)u*64))[q];    // 1KB wave load
      a[0] = fmaf(w, bfl(r.x), a[0]); a[1] = fmaf(w, bfh(r.x), a[1]);
      a[2] = fmaf(w, bfl(r.y), a[2]); a[3] = fmaf(w, bfh(r.y), a[3]);
      a[4] = fmaf(w, bfl(r.z), a[4]); a[5] = fmaf(w, bfh(r.z), a[5]);
      a[6] = fmaf(w, bfl(r.w), a[6]); a[7] = fmaf(w, bfh(r.w), a[7]);
    }
  }
  uint4 s = ((const uint4*)(t + (size_t)vg*64))[q];       // self row
  a[0] = fmaf(ps, bfl(s.x), a[0]); a[1] = fmaf(ps, bfh(s.x), a[1]);
  a[2] = fmaf(ps, bfl(s.y), a[2]); a[3] = fmaf(ps, bfh(s.y), a[3]);
  a[4] = fmaf(ps, bfl(s.z), a[4]); a[5] = fmaf(ps, bfh(s.z), a[5]);
  a[6] = fmaf(ps, bfl(s.w), a[6]); a[7] = fmaf(ps, bfh(s.w), a[7]);
  float4 b0 = ((const float4*)b)[2*q], b1v = ((const float4*)b)[2*q+1];
  float r0 = fmaxf(fmaf(a[0], inv, b0.x), 0.f),  r1 = fmaxf(fmaf(a[1], inv, b0.y), 0.f);
  float r2 = fmaxf(fmaf(a[2], inv, b0.z), 0.f),  r3 = fmaxf(fmaf(a[3], inv, b0.w), 0.f);
  float r4 = fmaxf(fmaf(a[4], inv, b1v.x), 0.f), r5 = fmaxf(fmaf(a[5], inv, b1v.y), 0.f);
  float r6 = fmaxf(fmaf(a[6], inv, b1v.z), 0.f), r7 = fmaxf(fmaf(a[7], inv, b1v.w), 0.f);
  uint4 o;
  o.x = (unsigned)f2bf(r0) | ((unsigned)f2bf(r1) << 16);
  o.y = (unsigned)f2bf(r2) | ((unsigned)f2bf(r3) << 16);
  o.z = (unsigned)f2bf(r4) | ((unsigned)f2bf(r5) << 16);
  o.w = (unsigned)f2bf(r6) | ((unsigned)f2bf(r7) << 16);
  if (vok) ((uint4*)(h + (size_t)vg*64))[q] = o;          // 128B store (bucket-local)
}

// heads + fused mean: uniform (scalar-path) row loads; femb via compile-time
// predicated pick from the SAME loads (no extra VMEM); 4-way acc split.
__global__ __launch_bounds__(256, 4) void k_heads(const unsigned short* __restrict__ h,
                        const float* __restrict__ Wcat, const float* __restrict__ bcat,
                        const float* __restrict__ Wb2, const float* __restrict__ bb2,
                        float* __restrict__ out_opt, float* __restrict__ out_bot,
                        float* __restrict__ emb_acc, int n){
  __shared__ float red[256];
  int lane = threadIdx.x & 63;
  int gw = blockIdx.x*4 + uwave();
  int nw = gridDim.x*4;
  float wreg[64];
  #pragma unroll
  for (int k = 0; k < 64; k++) wreg[k] = Wcat[k*64 + lane];
  float bcr  = bcat[lane];
  float wb2r = (lane >= 32) ? Wb2[lane-32] : 0.f;
  float bb2r = bb2[0];
  float femb = 0.f;
  int fk = lane >> 3;                         // my feature's uint4 slot
  for (int v = gw; v < n; v += nw){
    const uint4* xr = (const uint4*)(h + (size_t)v*64);   // uniform row (scalar path)
    float ac[4] = {bcr, 0.f, 0.f, 0.f};
    unsigned myw = 0;
    #pragma unroll
    for (int k8 = 0; k8 < 8; k8++){
      uint4 c = xr[k8];
      unsigned wd = (lane & 4) ? ((lane & 2) ? c.w : c.z)
                               : ((lane & 2) ? c.y : c.x);
      myw = (k8 == fk) ? wd : myw;            // own-feature pick, no extra load
      float s = 0.f;
      s = fmaf(bfl(c.x), wreg[k8*8+0], s);
      s = fmaf(bfh(c.x), wreg[k8*8+1], s);
      s = fmaf(bfl(c.y), wreg[k8*8+2], s);
      s = fmaf(bfh(c.y), wreg[k8*8+3], s);
      s = fmaf(bfl(c.z), wreg[k8*8+4], s);
      s = fmaf(bfh(c.z), wreg[k8*8+5], s);
      s = fmaf(bfl(c.w), wreg[k8*8+6], s);
      s = fmaf(bfh(c.w), wreg[k8*8+7], s);
      ac[k8 & 3] += s;                        // static idx (unrolled)
    }
    float acc = (ac[0] + ac[2]) + (ac[1] + ac[3]);
    femb += (lane & 1) ? bfh(myw) : bfl(myw);
    if (lane < 10) out_opt[(size_t)v*10 + lane] = acc;
    float contrib = fmaxf(acc, 0.f) * wb2r;   // 0 for lanes<32
    #pragma unroll
    for (int off = 32; off; off >>= 1) contrib += __shfl_xor(contrib, off);
    if (lane == 0) out_bot[v] = 1.f / (1.f + __expf(-(contrib + bb2r)));
  }
  red[threadIdx.x] = femb;
  __syncthreads();
  if (threadIdx.x < 64)
    atomicAdd(&emb_acc[threadIdx.x],
              red[threadIdx.x] + red[64+threadIdx.x] + red[128+threadIdx.x] + red[192+threadIdx.x]);
}

__global__ void k_embed(const float* __restrict__ emb_acc, float* __restrict__ out_emb,
                        float invn){
  if (threadIdx.x < 64) out_emb[threadIdx.x] = emb_acc[threadIdx.x] * invn;
}

extern "C" void kernel_launch(void* const* d_in, const int* in_sizes, int n_in,
                              void* d_out, int out_size, void* d_ws, size_t ws_size,
                              hipStream_t stream) {
  const float* x    = (const float*)d_in[0];
  const int*   ei   = (const int*)d_in[1];
  const float* W1   = (const float*)d_in[2];
  const float* b1   = (const float*)d_in[3];
  const float* W2   = (const float*)d_in[4];
  const float* a_s  = (const float*)d_in[5];
  const float* a_d  = (const float*)d_in[6];
  const float* b2   = (const float*)d_in[7];
  const float* W3   = (const float*)d_in[8];
  const float* b3   = (const float*)d_in[9];
  const float* Wopt = (const float*)d_in[10];
  const float* bopt = (const float*)d_in[11];
  const float* Wb1  = (const float*)d_in[12];
  const float* bb1  = (const float*)d_in[13];
  const float* Wb2  = (const float*)d_in[14];
  const float* bb2  = (const float*)d_in[15];

  int n = in_sizes[0] / 32;      // 100000
  int e = in_sizes[1] / 2;       // 1250000
  const int* src = ei;
  const int* dst = ei + e;

  char* ws = (char*)d_ws;
  size_t off = 0;
  auto alloc = [&](size_t bytes) -> void* {
    void* p = ws + off;
    off += (bytes + 255) & ~(size_t)255;
    return p;
  };
  int nb2 = (n + NP2 - 1) >> 7;  // 782 buckets
  int*            cnt     = (int*)           alloc((size_t)n * 4);
  int*            adj     = (int*)           alloc((size_t)n * CAP * 4);
  float*          als     = (float*)         alloc((size_t)(n+1) * 4);  // +pad score
  float*          ald     = (float*)         alloc((size_t)n * 4);
  unsigned short* xh      = (unsigned short*)alloc((size_t)(n+1) * 32 * 2); // +zero row
  unsigned short* tb      = (unsigned short*)alloc((size_t)(n+1) * 64 * 2); // +zero row
  unsigned short* hbuf    = (unsigned short*)alloc((size_t)n * 64 * 2);     // bf16 h
  float*          emb_acc = (float*)         alloc((size_t)64 * 4);
  float*          Wcat    = (float*)         alloc((size_t)4096 * 4);
  float*          bcat    = (float*)         alloc((size_t)64 * 4);
  int*            bcnt    = (int*)           alloc((size_t)nb2 * 4);
  int*            perm    = (int*)           alloc((size_t)n * 4);

  // pairs buffer overlays hbuf (pairs consumed by k_fill before k_agg32g writes hbuf)
  int pbcap = e / nb2 + 384;     // mean + ~9 sigma (Binomial per-bucket count)
  long pcap_max = ((long)n * 128) / ((long)nb2 * 8);
  if (pbcap > (int)pcap_max) pbcap = (int)pcap_max;
  uint2* pairs = (uint2*)hbuf;

  float* out_opt = (float*)d_out;
  float* out_bot = out_opt + (size_t)n * 10;
  float* out_emb = out_bot + n;

  int nb8    = (n + 7) / 8;
  int nbW    = (n + 31) / 32;      // 8-node-per-wave aggs: 32 nodes/block
  int nbN    = (n + 255) / 256;
  int nbP    = (e + 2047) / 2048;  // k_part: 2048 edges/block

  k_setup<<<nbN, 256, 0, stream>>>(Wopt, bopt, Wb1, bb1, Wcat, bcat,
                                   bcnt, tb, xh, emb_acc, als, n, nb2);
  k_part<<<nbP, 256, 0, stream>>>(src, dst, pairs, bcnt, e, nb2, pbcap);
  k_fill<<<nb2, 256, 0, stream>>>(pairs, bcnt, cnt, adj, perm, x, xh, pbcap, n);

  // layer 1: GCN(32->64) fused: degree-paired gather + epilogue gemm -> h1 (bf16)
  k_agg32g<<<nb8, 256, 0, stream>>>(xh, adj, cnt, perm, W1, b1, hbuf, n);

  // layer 2: GAT(64->64): gemm -> bf16 t2 + scores, single-pass 8/wave gather -> h2
  k_gemm_alpha<<<2048, 256, 0, stream>>>(hbuf, W2, a_s, a_d, tb, als, ald, n);
  k_gat_agg<<<nbW, 256, 0, stream>>>(tb, adj, cnt, perm, als, ald, b2, hbuf, n);

  // layer 3: GCN(64->64): gemm (pre-scaled) -> bf16 t3, 8/wave gather -> h3
  k_gemm_b<true><<<2048, 256, 0, stream>>>(hbuf, W3, cnt, tb, n);
  k_gcn_agg<<<nbW, 256, 0, stream>>>(tb, adj, cnt, perm, b3, hbuf, n);

  // heads (+fused mean), final scale
  k_heads<<<2048, 256, 0, stream>>>(hbuf, Wcat, bcat, Wb2, bb2,
                                    out_opt, out_bot, emb_acc, n);
  k_embed<<<1, 64, 0, stream>>>(emb_acc, out_emb, 1.0f / (float)n);
}

// Round 13
// 342.089 us; speedup vs baseline: 1.0650x; 1.0650x over previous
//
#include <hip/hip_runtime.h>
#include <hip/hip_bf16.h>

// WorkflowGNN: GCN(32->64)+ReLU, GAT(64->64,h=1)+ReLU, GCN(64->64)+ReLU,
// heads: opt [N,10], bottleneck [N,1], mean-embed [64]. f32 in/out.
// R28: REVERT the mean fusion. R26 (fused, 54us) and R27 (fused+ILP+grid,
// 75us) both regressed k_heads vs the pre-fusion version (<43us, never in
// top-5); the fusion itself is the cause (extra live state deoptimizes the
// wreg-resident row GEMM). Restored: R24 k_heads (grid 1024) + R24 k_mean.
// Kept from R27: gemm_b/gemm_alpha 4-way acc split + grid 2048 (net ~-8us).
// R26 (kept): gat_agg single-pass adjacency (u8/p8 in regs).
// R24 (kept): in-bucket degree sort in k_fill (perm) -> cmax ~ deg.
// R22 (kept): 8-node/wave aggs, no butterfly, adj pad slots = n (zero row),
// fused castscale in k_fill.
// R20 (kept): k_agg32g epilogue via constant-index v_readlane.
// R19 (kept): atomic-free adjacency build (exact buckets + LDS fill).

#define CAP 64
#define NP2 128          // nodes per bucket (LDS tile rows), = 1<<7
#define NB2MAX 800       // LDS cursor array bound (n <= 102400)

__device__ __forceinline__ int uwave(){                 // wave id, known-uniform
  return __builtin_amdgcn_readfirstlane(threadIdx.x >> 6);
}
__device__ __forceinline__ unsigned short f2bf(float f){ // RNE, finite inputs
  unsigned u = __float_as_uint(f);
  return (unsigned short)((u + 0x7fffu + ((u >> 16) & 1u)) >> 16);
}
__device__ __forceinline__ float bfl(unsigned u){ return __uint_as_float(u << 16); }
__device__ __forceinline__ float bfh(unsigned u){ return __uint_as_float(u & 0xffff0000u); }
__device__ __forceinline__ float rdlane(float v, int l){ // constant-lane broadcast
  return __uint_as_float(__builtin_amdgcn_readlane(__float_as_uint(v), l));
}

// setup: zero bcnt/pad-rows/emb_acc/als[n], pack Wcat/bcat
__global__ void k_setup(const float* __restrict__ Wopt, const float* __restrict__ bopt,
                        const float* __restrict__ Wb1, const float* __restrict__ bb1,
                        float* __restrict__ Wcat, float* __restrict__ bcat,
                        int* __restrict__ bcnt, unsigned short* __restrict__ tb,
                        unsigned short* __restrict__ xh, float* __restrict__ emb_acc,
                        float* __restrict__ als, int n, int nb2){
  int i = blockIdx.x*blockDim.x + threadIdx.x;
  if (i < nb2) bcnt[i] = 0;
  if (blockIdx.x == 0){
    int tid = threadIdx.x;
    for (int j = tid; j < 4096; j += 256){    // pack head weights
      int f = j >> 6, c = j & 63;
      float w = 0.f;
      if (c < 10)       w = Wopt[f*10 + c];
      else if (c >= 32) w = Wb1[f*32 + (c-32)];
      Wcat[j] = w;
    }
    if (tid < 64){
      float b = 0.f;
      if (tid < 10)       b = bopt[tid];
      else if (tid >= 32) b = bb1[tid-32];
      bcat[tid] = b;
      tb[(size_t)n*64 + tid] = 0;             // zero pad row (64-feat)
      emb_acc[tid] = 0.f;
      if (tid == 0) als[n] = 0.f;             // pad score
    }
    if (tid >= 64 && tid < 96) xh[(size_t)n*32 + (tid-64)] = 0;  // zero pad row (32-feat)
  }
}

// pass A: bin edges into exact dst-range buckets (bk = dst>>7). One coalesced
// read of src/dst, LDS-aggregated cursors -> ~nb2 global atomics per block.
__global__ __launch_bounds__(256) void k_part(const int* __restrict__ src,
                        const int* __restrict__ dst,
                        uint2* __restrict__ pairs, int* __restrict__ bcnt,
                        int e, int nb2, int pbcap){
  __shared__ int lcnt[NB2MAX];
  __shared__ int lbase[NB2MAX];
  int tid = threadIdx.x;
  for (int j = tid; j < nb2; j += 256) lcnt[j] = 0;
  __syncthreads();
  int i0 = blockIdx.x*2048 + tid*8;
  int d[8], s[8], bk[8], lp[8];
  int nv = e - i0;
  if (nv > 8) nv = 8;
  if (nv < 0) nv = 0;
  if (nv == 8){
    int4 d0 = *(const int4*)(dst + i0), d1 = *(const int4*)(dst + i0 + 4);
    int4 s0 = *(const int4*)(src + i0), s1 = *(const int4*)(src + i0 + 4);
    d[0]=d0.x; d[1]=d0.y; d[2]=d0.z; d[3]=d0.w;
    d[4]=d1.x; d[5]=d1.y; d[6]=d1.z; d[7]=d1.w;
    s[0]=s0.x; s[1]=s0.y; s[2]=s0.z; s[3]=s0.w;
    s[4]=s1.x; s[5]=s1.y; s[6]=s1.z; s[7]=s1.w;
  } else {
    #pragma unroll
    for (int j = 0; j < 8; j++){ d[j] = 0; s[j] = 0; }
    for (int j = 0; j < nv; j++){ d[j] = dst[i0+j]; s[j] = src[i0+j]; }
  }
  #pragma unroll
  for (int j = 0; j < 8; j++){
    if (j < nv){
      bk[j] = d[j] >> 7;                      // exact: bucket owns [bk*128, bk*128+128)
      lp[j] = atomicAdd(&lcnt[bk[j]], 1);
    }
  }
  __syncthreads();
  for (int j = tid; j < nb2; j += 256){
    int c = lcnt[j];
    if (c) lbase[j] = atomicAdd(&bcnt[j], c);
  }
  __syncthreads();
  #pragma unroll
  for (int j = 0; j < 8; j++){
    if (j < nv){
      int p = lbase[bk[j]] + lp[j];
      if (p < pbcap)
        pairs[(size_t)bk[j]*pbcap + p] = make_uint2((unsigned)d[j], (unsigned)s[j]);
    }
  }
}

// pass B: one block per bucket. adj rows built in LDS (LDS atomics only),
// slots pre-initialized to n (zero-row index). Emits IN-BUCKET degree-sorted
// perm (65-bin LDS counting sort) + fused cast-scale of its 128 x-rows.
__global__ __launch_bounds__(256) void k_fill(const uint2* __restrict__ pairs,
                        const int* __restrict__ bcnt, int* __restrict__ cnt,
                        int* __restrict__ adj, int* __restrict__ perm,
                        const float* __restrict__ x, unsigned short* __restrict__ xh,
                        int pbcap, int n){
  __shared__ int lc[NP2];
  __shared__ int ladj[NP2*CAP];               // 32KB
  __shared__ int lb[65];
  int b = blockIdx.x;
  int lo = b << 7;
  int nn = min(NP2, n - lo);
  int tid = threadIdx.x;
  for (int j = tid; j < NP2; j += 256) lc[j] = 0;
  if (tid < 65) lb[tid] = 0;
  int4 nfill = make_int4(n, n, n, n);
  for (int j = tid; j < NP2*CAP/4; j += 256) ((int4*)ladj)[j] = nfill;
  __syncthreads();
  int m = bcnt[b];
  if (m > pbcap) m = pbcap;
  const uint2* pb = pairs + (size_t)b*pbcap;
  for (int j = tid; j < m; j += 256){
    uint2 p = pb[j];
    int r = (int)p.x - lo;
    int pos = atomicAdd(&lc[r], 1);
    if (pos < CAP) ladj[(r << 6) + pos] = (int)p.y;
  }
  __syncthreads();
  int d = 0;
  if (tid < nn){
    int c = lc[tid];
    cnt[lo + tid] = c;
    d = min(c, CAP);
    atomicAdd(&lb[d], 1);                     // degree histogram
  }
  __syncthreads();
  if (tid == 0){                              // exclusive scan, 65 bins
    int s = 0;
    #pragma unroll 1
    for (int k = 0; k < 65; k++){ int c = lb[k]; lb[k] = s; s += c; }
  }
  __syncthreads();
  if (tid < nn){                              // scatter: lb doubles as cursor
    int p = atomicAdd(&lb[d], 1);
    perm[lo + p] = lo + tid;                  // in-bucket degree-sorted perm
  }
  int tot = nn << 4;                          // nn*64 ints / 4 per uint4
  uint4* ga = (uint4*)(adj + (size_t)lo*CAP);
  const uint4* la = (const uint4*)ladj;
  for (int j = tid; j < tot; j += 256) ga[j] = la[j];
  // fused cast-scale: nn rows x 32 feats, dv = rsqrt(lc[r]+1)
  int tf = nn << 3;                           // float4 count
  const float4* xr4 = (const float4*)(x + (size_t)lo*32);
  uint2* xo = (uint2*)(xh + (size_t)lo*32);
  for (int j = tid; j < tf; j += 256){
    int r = j >> 3;
    float dv = rsqrtf((float)(lc[r] + 1));
    float4 v = xr4[j];
    uint2 o;
    o.x = (unsigned)f2bf(v.x*dv) | ((unsigned)f2bf(v.y*dv) << 16);
    o.y = (unsigned)f2bf(v.z*dv) | ((unsigned)f2bf(v.w*dv) << 16);
    xo[j] = o;
  }
}

// layer-1 FUSED aggregate+gemm, DUAL-NODE (perm'd: pair degree-adjacent).
__global__ __launch_bounds__(256) void k_agg32g(const unsigned short* __restrict__ xh,
                          const int* __restrict__ adj, const int* __restrict__ cnt,
                          const int* __restrict__ perm,
                          const float* __restrict__ W1, const float* __restrict__ b1,
                          unsigned short* __restrict__ h, int n){
  int lane = threadIdx.x & 63;
  float wreg[32];
  #pragma unroll
  for (int k = 0; k < 32; k++) wreg[k] = W1[k*64 + lane];  // coalesced, once
  float br = b1[lane];
  int i0 = blockIdx.x*8 + uwave()*2;
  if (i0 >= n) return;                        // uniform
  int i1 = i0 + 1;
  bool has1 = i1 < n;
  int v0 = perm[i0];
  int v1 = perm[has1 ? i1 : i0];
  int cn0 = cnt[v0], cn1 = cnt[v1];
  int c0 = min(cn0, CAP), c1 = min(cn1, CAP);
  int ureg0 = n, ureg1 = n;                   // pad -> zero row
  if (lane < c0) ureg0 = (adj + (size_t)v0*CAP)[lane];
  if (lane < c1) ureg1 = (adj + (size_t)v1*CAP)[lane];
  int g = lane >> 3, q = lane & 7;
  float4 a0 = {0.f,0.f,0.f,0.f}, a1 = {0.f,0.f,0.f,0.f};
  int itm = (max(c0, c1) + 7) >> 3;           // degree-adjacent pair: ~c0/8
  #pragma unroll 2
  for (int jj = 0; jj < itm; jj++){
    int u0 = __shfl(ureg0, jj*8 + g);         // pad iters -> zero row (L1-hot)
    int u1 = __shfl(ureg1, jj*8 + g);
    uint2 r0 = ((const uint2*)(xh + (size_t)u0*32))[q];   // both loads in flight
    uint2 r1 = ((const uint2*)(xh + (size_t)u1*32))[q];
    a0.x += bfl(r0.x); a0.y += bfh(r0.x); a0.z += bfl(r0.y); a0.w += bfh(r0.y);
    a1.x += bfl(r1.x); a1.y += bfh(r1.x); a1.z += bfl(r1.y); a1.w += bfh(r1.y);
  }
  #pragma unroll
  for (int off = 8; off <= 32; off <<= 1){
    a0.x += __shfl_xor(a0.x, off); a0.y += __shfl_xor(a0.y, off);
    a0.z += __shfl_xor(a0.z, off); a0.w += __shfl_xor(a0.w, off);
    a1.x += __shfl_xor(a1.x, off); a1.y += __shfl_xor(a1.y, off);
    a1.z += __shfl_xor(a1.z, off); a1.w += __shfl_xor(a1.w, off);
  }
  uint2 s0 = ((const uint2*)(xh + (size_t)v0*32))[q];     // self rows (pre-scaled)
  uint2 s1 = ((const uint2*)(xh + (size_t)v1*32))[q];
  a0.x += bfl(s0.x); a0.y += bfh(s0.x); a0.z += bfl(s0.y); a0.w += bfh(s0.y);
  a1.x += bfl(s1.x); a1.y += bfh(s1.x); a1.z += bfl(s1.y); a1.w += bfh(s1.y);
  float dv0 = rsqrtf((float)(cn0 + 1)), dv1 = rsqrtf((float)(cn1 + 1));
  a0.x *= dv0; a0.y *= dv0; a0.z *= dv0; a0.w *= dv0;
  a1.x *= dv1; a1.y *= dv1; a1.z *= dv1; a1.w *= dv1;
  float h0 = br, h1v = br;                    // epilogue gemms via v_readlane (VALU)
  #pragma unroll
  for (int q2 = 0; q2 < 8; q2++){
    float w0x = rdlane(a0.x, q2), w1x = rdlane(a1.x, q2);
    float w0y = rdlane(a0.y, q2), w1y = rdlane(a1.y, q2);
    float w0z = rdlane(a0.z, q2), w1z = rdlane(a1.z, q2);
    float w0w = rdlane(a0.w, q2), w1w = rdlane(a1.w, q2);
    h0 = fmaf(w0x, wreg[q2*4+0], h0); h1v = fmaf(w1x, wreg[q2*4+0], h1v);
    h0 = fmaf(w0y, wreg[q2*4+1], h0); h1v = fmaf(w1y, wreg[q2*4+1], h1v);
    h0 = fmaf(w0z, wreg[q2*4+2], h0); h1v = fmaf(w1z, wreg[q2*4+2], h1v);
    h0 = fmaf(w0w, wreg[q2*4+3], h0); h1v = fmaf(w1w, wreg[q2*4+3], h1v);
  }
  h[(size_t)v0*64 + lane] = f2bf(fmaxf(h0, 0.f));   // 128B store (bucket-local)
  if (has1) h[(size_t)v1*64 + lane] = f2bf(fmaxf(h1v, 0.f));
}

// K=64 GEMM (bf16 in) -> bf16 out, optional pre-scale. 4-way acc split (ILP).
template<bool SCALE>
__global__ __launch_bounds__(256, 4) void k_gemm_b(const unsigned short* __restrict__ x,
                       const float* __restrict__ W, const int* __restrict__ cnt,
                       unsigned short* __restrict__ t, int n){
  int lane = threadIdx.x & 63;
  int gw = blockIdx.x*4 + uwave();
  int nw = gridDim.x*4;
  float wreg[64];
  #pragma unroll
  for (int k = 0; k < 64; k++) wreg[k] = W[k*64 + lane];
  for (int v = gw; v < n; v += nw){
    const uint4* xr = (const uint4*)(x + (size_t)v*64);   // uniform row, 8x16B
    float ac[4] = {0.f, 0.f, 0.f, 0.f};
    #pragma unroll
    for (int k8 = 0; k8 < 8; k8++){
      uint4 c = xr[k8];
      float s = 0.f;
      s = fmaf(bfl(c.x), wreg[k8*8+0], s);
      s = fmaf(bfh(c.x), wreg[k8*8+1], s);
      s = fmaf(bfl(c.y), wreg[k8*8+2], s);
      s = fmaf(bfh(c.y), wreg[k8*8+3], s);
      s = fmaf(bfl(c.z), wreg[k8*8+4], s);
      s = fmaf(bfh(c.z), wreg[k8*8+5], s);
      s = fmaf(bfl(c.w), wreg[k8*8+6], s);
      s = fmaf(bfh(c.w), wreg[k8*8+7], s);
      ac[k8 & 3] += s;                        // static idx (unrolled)
    }
    float acc = (ac[0] + ac[2]) + (ac[1] + ac[3]);
    if (SCALE) acc *= rsqrtf((float)(cnt[v] + 1));
    t[(size_t)v*64 + lane] = f2bf(acc);                    // 128B coalesced
  }
}

// K=64 GEMM + fused alpha dots. 4-way acc split (ILP).
__global__ __launch_bounds__(256, 4) void k_gemm_alpha(const unsigned short* __restrict__ x,
                       const float* __restrict__ W,
                       const float* __restrict__ asrc, const float* __restrict__ adst,
                       unsigned short* __restrict__ t, float* __restrict__ als,
                       float* __restrict__ ald, int n){
  int lane = threadIdx.x & 63;
  int gw = blockIdx.x*4 + uwave();
  int nw = gridDim.x*4;
  float wreg[64];
  #pragma unroll
  for (int k = 0; k < 64; k++) wreg[k] = W[k*64 + lane];
  float asr = asrc[lane], adr = adst[lane];
  for (int v = gw; v < n; v += nw){
    const uint4* xr = (const uint4*)(x + (size_t)v*64);
    float ac[4] = {0.f, 0.f, 0.f, 0.f};
    #pragma unroll
    for (int k8 = 0; k8 < 8; k8++){
      uint4 c = xr[k8];
      float s = 0.f;
      s = fmaf(bfl(c.x), wreg[k8*8+0], s);
      s = fmaf(bfh(c.x), wreg[k8*8+1], s);
      s = fmaf(bfl(c.y), wreg[k8*8+2], s);
      s = fmaf(bfh(c.y), wreg[k8*8+3], s);
      s = fmaf(bfl(c.z), wreg[k8*8+4], s);
      s = fmaf(bfh(c.z), wreg[k8*8+5], s);
      s = fmaf(bfl(c.w), wreg[k8*8+6], s);
      s = fmaf(bfh(c.w), wreg[k8*8+7], s);
      ac[k8 & 3] += s;                        // static idx (unrolled)
    }
    float acc = (ac[0] + ac[2]) + (ac[1] + ac[3]);
    t[(size_t)v*64 + lane] = f2bf(acc);
    float s1 = acc * asr, s2 = acc * adr;
    #pragma unroll
    for (int off = 32; off; off >>= 1){
      s1 += __shfl_xor(s1, off);
      s2 += __shfl_xor(s2, off);
    }
    if (lane == 0){ als[v] = s1; ald[v] = s2; }
  }
}

// GCN agg (layer 3): 8 degree-adjacent nodes/wave via in-bucket perm.
__global__ __launch_bounds__(256) void k_gcn_agg(const unsigned short* __restrict__ t,
                          const int* __restrict__ adj, const int* __restrict__ cnt,
                          const int* __restrict__ perm,
                          const float* __restrict__ b, unsigned short* __restrict__ h, int n){
  int lane = threadIdx.x & 63;
  int g = lane >> 3, q = lane & 7;
  int i0 = blockIdx.x*32 + uwave()*8;
  if (i0 >= n) return;                        // uniform
  int idx = i0 + g;
  bool vok = idx < n;
  int vg = perm[vok ? idx : n - 1];
  int cn = cnt[vg];
  int c = vok ? min(cn, CAP) : 0;
  int cm = c;                                 // wave max degree (~equal, sorted)
  cm = max(cm, __shfl_xor(cm, 8));
  cm = max(cm, __shfl_xor(cm, 16));
  cm = max(cm, __shfl_xor(cm, 32));
  int cmax = __builtin_amdgcn_readfirstlane(cm);
  const int* arow = adj + (size_t)vg*CAP;     // per-lane base
  float a[8] = {0,0,0,0,0,0,0,0};
  int bsel = (lane & 56);
  for (int blk = 0; blk*8 < cmax; blk++){
    int ureg = arow[blk*8 + q];               // 8 slots of own row (pad slots = n)
    #pragma unroll
    for (int j2 = 0; j2 < 8; j2++){
      int u = __shfl(ureg, bsel | j2);        // group-slot broadcast
      uint4 r = ((const uint4*)(t + (size_t)u*64))[q];    // 1KB wave load
      a[0] += bfl(r.x); a[1] += bfh(r.x); a[2] += bfl(r.y); a[3] += bfh(r.y);
      a[4] += bfl(r.z); a[5] += bfh(r.z); a[6] += bfl(r.w); a[7] += bfh(r.w);
    }
  }
  uint4 s = ((const uint4*)(t + (size_t)vg*64))[q];       // self row
  a[0] += bfl(s.x); a[1] += bfh(s.x); a[2] += bfl(s.y); a[3] += bfh(s.y);
  a[4] += bfl(s.z); a[5] += bfh(s.z); a[6] += bfl(s.w); a[7] += bfh(s.w);
  float dv = rsqrtf((float)(cn + 1));
  float4 b0 = ((const float4*)b)[2*q], b1v = ((const float4*)b)[2*q+1];
  float r0 = fmaxf(fmaf(a[0], dv, b0.x), 0.f),  r1 = fmaxf(fmaf(a[1], dv, b0.y), 0.f);
  float r2 = fmaxf(fmaf(a[2], dv, b0.z), 0.f),  r3 = fmaxf(fmaf(a[3], dv, b0.w), 0.f);
  float r4 = fmaxf(fmaf(a[4], dv, b1v.x), 0.f), r5 = fmaxf(fmaf(a[5], dv, b1v.y), 0.f);
  float r6 = fmaxf(fmaf(a[6], dv, b1v.z), 0.f), r7 = fmaxf(fmaf(a[7], dv, b1v.w), 0.f);
  uint4 o;
  o.x = (unsigned)f2bf(r0) | ((unsigned)f2bf(r1) << 16);
  o.y = (unsigned)f2bf(r2) | ((unsigned)f2bf(r3) << 16);
  o.z = (unsigned)f2bf(r4) | ((unsigned)f2bf(r5) << 16);
  o.w = (unsigned)f2bf(r6) | ((unsigned)f2bf(r7) << 16);
  if (vok) ((uint4*)(h + (size_t)vg*64))[q] = o;          // 128B store (bucket-local)
}

// GAT agg: 8 degree-adjacent nodes/wave, SINGLE adjacency pass (u8/p8 regs).
__global__ __launch_bounds__(256) void k_gat_agg(const unsigned short* __restrict__ t,
                          const int* __restrict__ adj, const int* __restrict__ cnt,
                          const int* __restrict__ perm,
                          const float* __restrict__ als, const float* __restrict__ ald,
                          const float* __restrict__ b, unsigned short* __restrict__ h, int n){
  int lane = threadIdx.x & 63;
  int g = lane >> 3, q = lane & 7;
  int i0 = blockIdx.x*32 + uwave()*8;
  if (i0 >= n) return;                        // uniform
  int idx = i0 + g;
  bool vok = idx < n;
  int vg = perm[vok ? idx : n - 1];
  int c = vok ? min(cnt[vg], CAP) : 0;
  int cm = c;
  cm = max(cm, __shfl_xor(cm, 8));
  cm = max(cm, __shfl_xor(cm, 16));
  cm = max(cm, __shfl_xor(cm, 32));
  int cmax = __builtin_amdgcn_readfirstlane(cm);
  const int* arow = adj + (size_t)vg*CAP;
  float adv = ald[vg];
  float es = als[vg] + adv; es = es > 0.f ? es : 0.2f*es;
  int u8[8];
  float p8[8];
  #pragma unroll
  for (int r = 0; r < 8; r++){ u8[r] = n; p8[r] = -1e30f; }
  float em = es;
  #pragma unroll
  for (int r = 0; r < 8; r++){
    if (r*8 >= cmax) break;                   // uniform
    int slot = r*8 + q;
    int u = arow[slot];                       // pad slot -> n (als[n]=0)
    u8[r] = u;
    float ev = als[u] + adv; ev = ev > 0.f ? ev : 0.2f*ev;
    p8[r] = (slot < c) ? ev : -1e30f;
    em = fmaxf(em, p8[r]);
  }
  em = fmaxf(em, __shfl_xor(em, 1));
  em = fmaxf(em, __shfl_xor(em, 2));
  em = fmaxf(em, __shfl_xor(em, 4));
  float sm = 0.f;
  #pragma unroll
  for (int r = 0; r < 8; r++){
    if (r*8 >= cmax) break;                   // uniform
    float pv = __expf(p8[r] - em);            // masked slots -> exp(-1e30)=0
    p8[r] = pv;                               // store final edge weight
    sm += pv;
  }
  sm += __shfl_xor(sm, 1);
  sm += __shfl_xor(sm, 2);
  sm += __shfl_xor(sm, 4);
  float ps = __expf(es - em);
  float inv = 1.f / (sm + ps);
  float a[8] = {0,0,0,0,0,0,0,0};
  int bsel = (lane & 56);
  #pragma unroll
  for (int blk = 0; blk < 8; blk++){          // static idx into u8/p8 (rule #20)
    if (blk*8 >= cmax) break;                 // uniform
    #pragma unroll
    for (int j2 = 0; j2 < 8; j2++){
      int   u = __shfl(u8[blk], bsel | j2);   // group-slot broadcast
      float w = __shfl(p8[blk], bsel | j2);   // precomputed weight (0 for pads)
      uint4 r = ((const uint4*)(t + (size_t)u*64))[q];    // 1KB wave load
      a[0] = fmaf(w, bfl(r.x), a[0]); a[1] = fmaf(w, bfh(r.x), a[1]);
      a[2] = fmaf(w, bfl(r.y), a[2]); a[3] = fmaf(w, bfh(r.y), a[3]);
      a[4] = fmaf(w, bfl(r.z), a[4]); a[5] = fmaf(w, bfh(r.z), a[5]);
      a[6] = fmaf(w, bfl(r.w), a[6]); a[7] = fmaf(w, bfh(r.w), a[7]);
    }
  }
  uint4 s = ((const uint4*)(t + (size_t)vg*64))[q];       // self row
  a[0] = fmaf(ps, bfl(s.x), a[0]); a[1] = fmaf(ps, bfh(s.x), a[1]);
  a[2] = fmaf(ps, bfl(s.y), a[2]); a[3] = fmaf(ps, bfh(s.y), a[3]);
  a[4] = fmaf(ps, bfl(s.z), a[4]); a[5] = fmaf(ps, bfh(s.z), a[5]);
  a[6] = fmaf(ps, bfl(s.w), a[6]); a[7] = fmaf(ps, bfh(s.w), a[7]);
  float4 b0 = ((const float4*)b)[2*q], b1v = ((const float4*)b)[2*q+1];
  float r0 = fmaxf(fmaf(a[0], inv, b0.x), 0.f),  r1 = fmaxf(fmaf(a[1], inv, b0.y), 0.f);
  float r2 = fmaxf(fmaf(a[2], inv, b0.z), 0.f),  r3 = fmaxf(fmaf(a[3], inv, b0.w), 0.f);
  float r4 = fmaxf(fmaf(a[4], inv, b1v.x), 0.f), r5 = fmaxf(fmaf(a[5], inv, b1v.y), 0.f);
  float r6 = fmaxf(fmaf(a[6], inv, b1v.z), 0.f), r7 = fmaxf(fmaf(a[7], inv, b1v.w), 0.f);
  uint4 o;
  o.x = (unsigned)f2bf(r0) | ((unsigned)f2bf(r1) << 16);
  o.y = (unsigned)f2bf(r2) | ((unsigned)f2bf(r3) << 16);
  o.z = (unsigned)f2bf(r4) | ((unsigned)f2bf(r5) << 16);
  o.w = (unsigned)f2bf(r6) | ((unsigned)f2bf(r7) << 16);
  if (vok) ((uint4*)(h + (size_t)vg*64))[q] = o;          // 128B store (bucket-local)
}

// heads (R24 proven version): dense Wcat/bcat, resident wreg[64], bf16 h.
__global__ __launch_bounds__(256, 4) void k_heads(const unsigned short* __restrict__ h,
                        const float* __restrict__ Wcat, const float* __restrict__ bcat,
                        const float* __restrict__ Wb2, const float* __restrict__ bb2,
                        float* __restrict__ out_opt, float* __restrict__ out_bot, int n){
  int lane = threadIdx.x & 63;
  int gw = blockIdx.x*4 + uwave();
  int nw = gridDim.x*4;
  float wreg[64];
  #pragma unroll
  for (int k = 0; k < 64; k++) wreg[k] = Wcat[k*64 + lane];
  float bcr  = bcat[lane];
  float wb2r = (lane >= 32) ? Wb2[lane-32] : 0.f;
  float bb2r = bb2[0];
  for (int v = gw; v < n; v += nw){
    const uint4* xr = (const uint4*)(h + (size_t)v*64);   // uniform row, 8x16B
    float acc = bcr;
    #pragma unroll
    for (int k8 = 0; k8 < 8; k8++){
      uint4 c = xr[k8];
      acc = fmaf(bfl(c.x), wreg[k8*8+0], acc);
      acc = fmaf(bfh(c.x), wreg[k8*8+1], acc);
      acc = fmaf(bfl(c.y), wreg[k8*8+2], acc);
      acc = fmaf(bfh(c.y), wreg[k8*8+3], acc);
      acc = fmaf(bfl(c.z), wreg[k8*8+4], acc);
      acc = fmaf(bfh(c.z), wreg[k8*8+5], acc);
      acc = fmaf(bfl(c.w), wreg[k8*8+6], acc);
      acc = fmaf(bfh(c.w), wreg[k8*8+7], acc);
    }
    if (lane < 10) out_opt[(size_t)v*10 + lane] = acc;
    float contrib = fmaxf(acc, 0.f) * wb2r;   // 0 for lanes<32
    #pragma unroll
    for (int off = 32; off; off >>= 1) contrib += __shfl_xor(contrib, off);
    if (lane == 0) out_bot[v] = 1.f / (1.f + __expf(-(contrib + bb2r)));
  }
}

// mean embedding partials over bf16 h (R24 proven): block-reduce, 64-addr atomics
__global__ __launch_bounds__(256) void k_mean(const unsigned short* __restrict__ h,
                       float* __restrict__ emb_acc, int n){
  __shared__ float red[256];
  int tid = threadIdx.x;
  int w = tid >> 6, lane = tid & 63;
  float s = 0.f;
  for (int r = blockIdx.x*4 + w; r < n; r += 1024)
    s += __uint_as_float(((unsigned)h[(size_t)r*64 + lane]) << 16);
  red[tid] = s;
  __syncthreads();
  if (tid < 64)
    atomicAdd(&emb_acc[tid], red[tid] + red[64+tid] + red[128+tid] + red[192+tid]);
}

__global__ void k_embed(const float* __restrict__ emb_acc, float* __restrict__ out_emb,
                        float invn){
  if (threadIdx.x < 64) out_emb[threadIdx.x] = emb_acc[threadIdx.x] * invn;
}

extern "C" void kernel_launch(void* const* d_in, const int* in_sizes, int n_in,
                              void* d_out, int out_size, void* d_ws, size_t ws_size,
                              hipStream_t stream) {
  const float* x    = (const float*)d_in[0];
  const int*   ei   = (const int*)d_in[1];
  const float* W1   = (const float*)d_in[2];
  const float* b1   = (const float*)d_in[3];
  const float* W2   = (const float*)d_in[4];
  const float* a_s  = (const float*)d_in[5];
  const float* a_d  = (const float*)d_in[6];
  const float* b2   = (const float*)d_in[7];
  const float* W3   = (const float*)d_in[8];
  const float* b3   = (const float*)d_in[9];
  const float* Wopt = (const float*)d_in[10];
  const float* bopt = (const float*)d_in[11];
  const float* Wb1  = (const float*)d_in[12];
  const float* bb1  = (const float*)d_in[13];
  const float* Wb2  = (const float*)d_in[14];
  const float* bb2  = (const float*)d_in[15];

  int n = in_sizes[0] / 32;      // 100000
  int e = in_sizes[1] / 2;       // 1250000
  const int* src = ei;
  const int* dst = ei + e;

  char* ws = (char*)d_ws;
  size_t off = 0;
  auto alloc = [&](size_t bytes) -> void* {
    void* p = ws + off;
    off += (bytes + 255) & ~(size_t)255;
    return p;
  };
  int nb2 = (n + NP2 - 1) >> 7;  // 782 buckets
  int*            cnt     = (int*)           alloc((size_t)n * 4);
  int*            adj     = (int*)           alloc((size_t)n * CAP * 4);
  float*          als     = (float*)         alloc((size_t)(n+1) * 4);  // +pad score
  float*          ald     = (float*)         alloc((size_t)n * 4);
  unsigned short* xh      = (unsigned short*)alloc((size_t)(n+1) * 32 * 2); // +zero row
  unsigned short* tb      = (unsigned short*)alloc((size_t)(n+1) * 64 * 2); // +zero row
  unsigned short* hbuf    = (unsigned short*)alloc((size_t)n * 64 * 2);     // bf16 h
  float*          emb_acc = (float*)         alloc((size_t)64 * 4);
  float*          Wcat    = (float*)         alloc((size_t)4096 * 4);
  float*          bcat    = (float*)         alloc((size_t)64 * 4);
  int*            bcnt    = (int*)           alloc((size_t)nb2 * 4);
  int*            perm    = (int*)           alloc((size_t)n * 4);

  // pairs buffer overlays hbuf (pairs consumed by k_fill before k_agg32g writes hbuf)
  int pbcap = e / nb2 + 384;     // mean + ~9 sigma (Binomial per-bucket count)
  long pcap_max = ((long)n * 128) / ((long)nb2 * 8);
  if (pbcap > (int)pcap_max) pbcap = (int)pcap_max;
  uint2* pairs = (uint2*)hbuf;

  float* out_opt = (float*)d_out;
  float* out_bot = out_opt + (size_t)n * 10;
  float* out_emb = out_bot + n;

  int nb8    = (n + 7) / 8;
  int nbW    = (n + 31) / 32;      // 8-node-per-wave aggs: 32 nodes/block
  int nbN    = (n + 255) / 256;
  int nbP    = (e + 2047) / 2048;  // k_part: 2048 edges/block

  k_setup<<<nbN, 256, 0, stream>>>(Wopt, bopt, Wb1, bb1, Wcat, bcat,
                                   bcnt, tb, xh, emb_acc, als, n, nb2);
  k_part<<<nbP, 256, 0, stream>>>(src, dst, pairs, bcnt, e, nb2, pbcap);
  k_fill<<<nb2, 256, 0, stream>>>(pairs, bcnt, cnt, adj, perm, x, xh, pbcap, n);

  // layer 1: GCN(32->64) fused: degree-paired gather + epilogue gemm -> h1 (bf16)
  k_agg32g<<<nb8, 256, 0, stream>>>(xh, adj, cnt, perm, W1, b1, hbuf, n);

  // layer 2: GAT(64->64): gemm -> bf16 t2 + scores, single-pass 8/wave gather -> h2
  k_gemm_alpha<<<2048, 256, 0, stream>>>(hbuf, W2, a_s, a_d, tb, als, ald, n);
  k_gat_agg<<<nbW, 256, 0, stream>>>(tb, adj, cnt, perm, als, ald, b2, hbuf, n);

  // layer 3: GCN(64->64): gemm (pre-scaled) -> bf16 t3, 8/wave gather -> h3
  k_gemm_b<true><<<2048, 256, 0, stream>>>(hbuf, W3, cnt, tb, n);
  k_gcn_agg<<<nbW, 256, 0, stream>>>(tb, adj, cnt, perm, b3, hbuf, n);

  // heads, mean, final scale
  k_heads<<<1024, 256, 0, stream>>>(hbuf, Wcat, bcat, Wb2, bb2,
                                    out_opt, out_bot, n);
  k_mean<<<256, 256, 0, stream>>>(hbuf, emb_acc, n);
  k_embed<<<1, 64, 0, stream>>>(emb_acc, out_emb, 1.0f / (float)n);
}